// Round 5
// baseline (3246.470 us; speedup 1.0000x reference)
//
#include <hip/hip_runtime.h>
#include <stdint.h>

// N=64, T=128, D=512, H=1024, 4H=4096.
// R4: persistent kernel, ONE cross-wg hop per step.
//   - 256 gemm wgs (R=wid>>7 rows [32R,32R+32), C=wid&127 h-cols [8C,8C+8))
//   - 16 dedicated score wgs (wids 256..271, 4 rows each, 1 row/wave):
//     read h(t) directly, compute scores+softmax, publish wflag. No pscore.
//   - LDS 73 KB -> 2 wg/CU, grid 272 <= capacity 512 (no deadlock).
//   - All cross-wg data via agent-relaxed atomic ull (sc1) + release flags.
//   xwx[n,t,:]  = x[n,t,:]@Wx + b        (precomputed bf16 MFMA GEMM)
//   P2[n,col,l] = Af[n,:,l]@Wattn[:,col] (precomputed bf16 MFMA GEMM)

#define Tt 128
#define FH 4096

typedef __bf16 bf8 __attribute__((ext_vector_type(8)));
typedef float f4 __attribute__((ext_vector_type(4)));
typedef short s8v __attribute__((ext_vector_type(8)));
typedef unsigned long long ull;

__device__ __forceinline__ float bf2f(unsigned short u) {
    union { unsigned u32; float f; } x; x.u32 = ((unsigned)u) << 16; return x.f;
}
__device__ __forceinline__ unsigned short f2bf(float f) {
    union { float f32; unsigned u; } x; x.f32 = f;
    unsigned r = x.u + 0x7fffu + ((x.u >> 16) & 1u);
    return (unsigned short)(r >> 16);
}
__device__ __forceinline__ ull ald(const ull* p) {
    return __hip_atomic_load((ull*)p, __ATOMIC_RELAXED, __HIP_MEMORY_SCOPE_AGENT);
}
__device__ __forceinline__ void ast(ull* p, ull v) {
    __hip_atomic_store(p, v, __ATOMIC_RELAXED, __HIP_MEMORY_SCOPE_AGENT);
}

// ---------------- converts / init ----------------

__global__ __launch_bounds__(256) void k_cast_bf16(const float* __restrict__ in,
                                                   unsigned short* __restrict__ out, int n) {
    int i = blockIdx.x * 256 + threadIdx.x;
    if (i < n) out[i] = f2bf(in[i]);
}

__global__ __launch_bounds__(256) void k_transpose_bf16(const float* __restrict__ W,
                                                        unsigned short* __restrict__ WT, int K) {
    __shared__ float tl[32][33];
    int c0 = blockIdx.x * 32, k0 = blockIdx.y * 32;
    int tx = threadIdx.x & 31, ty = threadIdx.x >> 5;
    #pragma unroll
    for (int i = 0; i < 32; i += 8) tl[ty + i][tx] = W[(size_t)(k0 + ty + i) * 4096 + c0 + tx];
    __syncthreads();
    #pragma unroll
    for (int i = 0; i < 32; i += 8) WT[(size_t)(c0 + ty + i) * K + k0 + tx] = f2bf(tl[tx][ty + i]);
}

__global__ __launch_bounds__(256) void k_afl(const float* __restrict__ A,
                                             unsigned short* __restrict__ Afl) {
    int idx = blockIdx.x * 256 + threadIdx.x;
    int k = idx & 1023, l = (idx >> 10) & 15, n = idx >> 14;
    Afl[idx] = f2bf(A[((size_t)n * 1024 + k) * 16 + l]);
}

__global__ __launch_bounds__(256) void k_init(const float* __restrict__ A,
                                              float* __restrict__ cstate,
                                              unsigned short* __restrict__ hbf) {
    int idx = blockIdx.x * 256 + threadIdx.x;   // 64*1024
    const float* ap = A + (size_t)idx * 16;
    float s = 0.f;
    #pragma unroll
    for (int l = 0; l < 16; l++) s += ap[l];
    float h = s * (1.0f / 16.0f);
    cstate[idx] = h;
    hbf[idx] = f2bf(h);
}

// ---------------- generic bf16 MFMA GEMM (preamble) ----------------
__global__ __launch_bounds__(256) void k_gemm(const unsigned short* __restrict__ A,
                                              const unsigned short* __restrict__ BT,
                                              const float* __restrict__ bias,
                                              unsigned short* __restrict__ out,
                                              int M, int Nn, int K, int mode) {
    __shared__ unsigned short As[128][40];
    __shared__ unsigned short Bs[128][40];
    int m0 = blockIdx.y * 128, n0 = blockIdx.x * 128;
    int tid = threadIdx.x, lane = tid & 63, wave = tid >> 6;
    int wr = wave >> 1, wc = wave & 1, quad = lane >> 4, l16 = lane & 15;
    f4 acc[4][4];
    #pragma unroll
    for (int i = 0; i < 4; i++)
        #pragma unroll
        for (int j = 0; j < 4; j++) acc[i][j] = f4{0.f, 0.f, 0.f, 0.f};

    for (int k0 = 0; k0 < K; k0 += 32) {
        __syncthreads();
        #pragma unroll
        for (int i = 0; i < 2; i++) {
            int idx = i * 256 + tid, r = idx >> 2, c = idx & 3;
            *(s8v*)&As[r][c * 8] = *(const s8v*)&A[(size_t)(m0 + r) * K + k0 + c * 8];
            *(s8v*)&Bs[r][c * 8] = *(const s8v*)&BT[(size_t)(n0 + r) * K + k0 + c * 8];
        }
        __syncthreads();
        bf8 af[4], bfr[4];
        #pragma unroll
        for (int i = 0; i < 4; i++) af[i] = *(const bf8*)&As[wr * 64 + i * 16 + l16][quad * 8];
        #pragma unroll
        for (int j = 0; j < 4; j++) bfr[j] = *(const bf8*)&Bs[wc * 64 + j * 16 + l16][quad * 8];
        #pragma unroll
        for (int i = 0; i < 4; i++)
            #pragma unroll
            for (int j = 0; j < 4; j++)
                acc[i][j] = __builtin_amdgcn_mfma_f32_16x16x32_bf16(af[i], bfr[j], acc[i][j], 0, 0, 0);
    }

    #pragma unroll
    for (int i = 0; i < 4; i++)
        #pragma unroll
        for (int j = 0; j < 4; j++) {
            int row0 = m0 + wr * 64 + i * 16 + quad * 4;
            int col = n0 + wc * 64 + j * 16 + l16;
            float bia = bias ? bias[col] : 0.0f;
            #pragma unroll
            for (int r = 0; r < 4; r++) {
                float v = acc[i][j][r] + bia;
                int rw = row0 + r;
                if (mode == 0) {
                    out[(size_t)rw * Nn + col] = f2bf(v);
                } else {
                    int n = rw >> 4, l = rw & 15;
                    out[((size_t)n * Nn + col) * 16 + l] = f2bf(v);
                }
            }
        }
}

// ---------------- persistent recurrent kernel ----------------
__global__ __launch_bounds__(256, 2) void k_recur(
    const float* __restrict__ Afull,
    const unsigned short* __restrict__ WhT, const unsigned short* __restrict__ xwx,
    const unsigned short* __restrict__ P2, const float* __restrict__ cstate,
    unsigned short* __restrict__ hbuf,   // 2 x 65536 bf16 ping-pong
    float* __restrict__ wbuf,            // 64 x 16 f32 softmax weights
    int* __restrict__ wflag, int* __restrict__ hflag,
    float* __restrict__ out) {
    __shared__ unsigned short hL[32][1032];  // 66 KB (+8 pad/row: 2-way alias only)
    __shared__ float aL[32][33];             // 4.2 KB preactivation exchange
    __shared__ float wL[512];                // 2 KB softmax weights [32][16]
    __shared__ unsigned short hpk[32][8];    // 0.5 KB h pack buffer
    // total ~72.8 KB -> 2 wg/CU

    const int wid = blockIdx.x;
    const int tid = threadIdx.x, lane = tid & 63, wave = tid >> 6;
    ull* wbuf_u = (ull*)wbuf;

    if (wid >= 256) {
        // ---------------- score wg: 4 rows, one per wave ----------------
        const int s = wid - 256;        // 0..15
        const int g = s >> 3;           // row group (0: rows 0-31, 1: rows 32-63)
        const int row = s * 4 + wave;   // n in 0..63
        const int k0 = lane * 16;
        const float* Ab = Afull + ((size_t)row * 1024 + k0) * 16;

        for (int t = 0; t < Tt; ++t) {
            if (tid < 128) {
                while (__hip_atomic_load(&hflag[g * 128 + tid], __ATOMIC_RELAXED,
                                         __HIP_MEMORY_SCOPE_AGENT) < t)
                    __builtin_amdgcn_s_sleep(1);
            }
            __syncthreads();
            __builtin_amdgcn_fence(__ATOMIC_ACQUIRE, "workgroup");

            const ull* hb_u = (const ull*)(hbuf + (t & 1) * 65536);
            float hk[16];
            #pragma unroll
            for (int i = 0; i < 4; i++) {
                union { ull u; unsigned short h[4]; } cv;
                cv.u = ald(hb_u + (size_t)row * 256 + lane * 4 + i);
                #pragma unroll
                for (int j = 0; j < 4; j++) hk[i * 4 + j] = bf2f(cv.h[j]);
            }
            float part[16];
            #pragma unroll
            for (int l = 0; l < 16; l++) part[l] = 0.f;
            #pragma unroll
            for (int kk = 0; kk < 16; ++kk) {
                const f4* ar = (const f4*)(Ab + (size_t)kk * 16);
                f4 a0 = ar[0], a1 = ar[1], a2 = ar[2], a3 = ar[3];
                float hv = hk[kk];
                part[0]  += hv * a0.x;  part[1]  += hv * a0.y;
                part[2]  += hv * a0.z;  part[3]  += hv * a0.w;
                part[4]  += hv * a1.x;  part[5]  += hv * a1.y;
                part[6]  += hv * a1.z;  part[7]  += hv * a1.w;
                part[8]  += hv * a2.x;  part[9]  += hv * a2.y;
                part[10] += hv * a2.z;  part[11] += hv * a2.w;
                part[12] += hv * a3.x;  part[13] += hv * a3.y;
                part[14] += hv * a3.z;  part[15] += hv * a3.w;
            }
            #pragma unroll
            for (int l = 0; l < 16; l++) {
                float v = part[l];
                v += __shfl_down(v, 32, 64); v += __shfl_down(v, 16, 64);
                v += __shfl_down(v, 8, 64);  v += __shfl_down(v, 4, 64);
                v += __shfl_down(v, 2, 64);  v += __shfl_down(v, 1, 64);
                part[l] = v;
            }
            if (lane == 0) {
                float sc[16]; float mx = -1e30f;
                #pragma unroll
                for (int l = 0; l < 16; l++) {
                    sc[l] = part[l] * (1.0f / 32.0f);
                    mx = fmaxf(mx, sc[l]);
                }
                float sum = 0.f;
                #pragma unroll
                for (int l = 0; l < 16; l++) { sc[l] = __expf(sc[l] - mx); sum += sc[l]; }
                float inv = 1.0f / sum;
                #pragma unroll
                for (int i = 0; i < 8; i++) {
                    union { ull u; float f[2]; } cv;
                    cv.f[0] = sc[2 * i] * inv; cv.f[1] = sc[2 * i + 1] * inv;
                    ast(wbuf_u + row * 8 + i, cv.u);
                }
                __hip_atomic_store(&wflag[row], t + 1, __ATOMIC_RELEASE,
                                   __HIP_MEMORY_SCOPE_AGENT);
            }
        }
        return;
    }

    // ---------------- gemm wg ----------------
    const int R = wid >> 7, C = wid & 127;
    const int quad = lane >> 4, l16 = lane & 15;
    const int rr = wave >> 1, cc = wave & 1;
    const int n_l = tid & 31, jl = tid >> 5;
    const int myn = R * 32 + n_l, myj = C * 8 + jl;
    const int cl = cc * 16 + l16;
    const int acol = ((cl >> 3) << 10) + C * 8 + (cl & 7);
    const size_t bbase = (size_t)acol * 1024 + quad * 8;

    float creg = cstate[(size_t)myn * 1024 + myj];   // c0 = h0, register-resident

    for (int t = 0; t < Tt; ++t) {
        const ull* hb_u = (const ull*)(hbuf + (t & 1) * 65536);
        ull* hbW_u = (ull*)(hbuf + ((t + 1) & 1) * 65536);

        // ---- wait for h(t) from all 128 same-group producers ----
        if (tid < 128) {
            while (__hip_atomic_load(&hflag[R * 128 + tid], __ATOMIC_RELAXED,
                                     __HIP_MEMORY_SCOPE_AGENT) < t)
                __builtin_amdgcn_s_sleep(1);
        }
        __syncthreads();
        __builtin_amdgcn_fence(__ATOMIC_ACQUIRE, "workgroup");

        // ---- stage h(t) rows [32R,32R+32) into LDS ----
        #pragma unroll
        for (int it = 0; it < 32; ++it) {
            int idx = it * 256 + tid;
            int r2 = idx >> 8, c8 = idx & 255;
            ull v = ald(hb_u + ((size_t)(R * 32 + r2) << 8) + c8);
            *(ull*)&hL[r2][c8 * 4] = v;
        }
        __syncthreads();

        // ---- GEMM: h@Wh, A from LDS, B (64 KB slice) from L2 ----
        f4 acc = {0.f, 0.f, 0.f, 0.f};
        const unsigned short* hrow = &hL[rr * 16 + l16][quad * 8];
        #pragma unroll 8
        for (int ks = 0; ks < 32; ++ks) {
            bf8 a = *(const bf8*)(hrow + ks * 32);
            bf8 b = *(const bf8*)(WhT + bbase + ks * 32);
            acc = __builtin_amdgcn_mfma_f32_16x16x32_bf16(a, b, acc, 0, 0, 0);
        }

        // ---- softmax weights (computed concurrently by score wgs) ----
        if (tid < 32) {
            while (__hip_atomic_load(&wflag[R * 32 + tid], __ATOMIC_RELAXED,
                                     __HIP_MEMORY_SCOPE_AGENT) < t + 1)
                __builtin_amdgcn_s_sleep(1);
        }
        __syncthreads();
        __builtin_amdgcn_fence(__ATOMIC_ACQUIRE, "workgroup");
        {
            union { ull u; float f[2]; } cv;
            cv.u = ald(wbuf_u + R * 256 + tid);
            wL[tid * 2] = cv.f[0]; wL[tid * 2 + 1] = cv.f[1];
        }
        __syncthreads();

        // ---- epilogue: + xwx + attention (P-form) -> aL ----
        #pragma unroll
        for (int r = 0; r < 4; r++) {
            int nl = rr * 16 + quad * 4 + r;
            int n = R * 32 + nl;
            float v = acc[r] + bf2f(xwx[((size_t)n * Tt + t) * FH + acol]);
            const unsigned short* pp = P2 + ((size_t)n * FH + acol) * 16;
            s8v p0 = *(const s8v*)pp;
            s8v p1 = *(const s8v*)(pp + 8);
            float s = 0.f;
            #pragma unroll
            for (int l = 0; l < 8; l++) s += wL[nl * 16 + l] * bf2f((unsigned short)p0[l]);
            #pragma unroll
            for (int l = 0; l < 8; l++) s += wL[nl * 16 + 8 + l] * bf2f((unsigned short)p1[l]);
            aL[nl][cl] = v + s;
        }
        __syncthreads();

        // ---- gates (c register-resident) ----
        {
            float iv = aL[n_l][jl],      fv = aL[n_l][8 + jl];
            float ov = aL[n_l][16 + jl], gv = aL[n_l][24 + jl];
            float ig = 1.f / (1.f + __expf(-iv));
            float fg = 1.f / (1.f + __expf(-fv));
            float og = 1.f / (1.f + __expf(-ov));
            float gg = tanhf(gv);
            creg = fg * creg + ig * gg;
            float hv = og * tanhf(creg);
            __hip_atomic_store(&out[((size_t)myn * Tt + t) * 1024 + myj], hv,
                               __ATOMIC_RELAXED, __HIP_MEMORY_SCOPE_AGENT);
            hpk[n_l][jl] = f2bf(hv);
        }
        __syncthreads();

        // ---- publish h(t+1) chunk + flag ----
        if (tid < 64) {
            int row = tid >> 1, half = tid & 1;
            ull v = *(const ull*)&hpk[row][half * 4];
            ast(hbW_u + ((size_t)(R * 32 + row) << 8) + C * 2 + half, v);
        }
        __syncthreads();   // drains all waves' stores before flag publish
        if (tid == 0)
            __hip_atomic_store(&hflag[wid], t + 1, __ATOMIC_RELEASE,
                               __HIP_MEMORY_SCOPE_AGENT);
    }
}

// ---------------- launch ----------------

extern "C" void kernel_launch(void* const* d_in, const int* in_sizes, int n_in,
                              void* d_out, int out_size, void* d_ws, size_t ws_size,
                              hipStream_t stream) {
    const float* x     = (const float*)d_in[0];   // [64][128][512]
    const float* A     = (const float*)d_in[1];   // [64][1024][16]
    const float* Wx    = (const float*)d_in[2];   // [512][4096]
    const float* Wh    = (const float*)d_in[3];   // [1024][4096]
    const float* Wattn = (const float*)d_in[4];   // [1024][4096]
    const float* b     = (const float*)d_in[5];   // [4096]
    float* out = (float*)d_out;
    char* ws = (char*)d_ws;

    unsigned short* xbf    = (unsigned short*)(ws);                // 8 MB; reused for P2
    unsigned short* P2     = (unsigned short*)(ws);                // alias (xbf dead by then)
    unsigned short* WxT    = (unsigned short*)(ws + 8388608);      // 4 MB
    unsigned short* WhT    = (unsigned short*)(ws + 12582912);     // 8 MB
    unsigned short* WattnT = (unsigned short*)(ws + 20971520);     // 8 MB
    unsigned short* Afl    = (unsigned short*)(ws + 29360128);     // 2 MB
    unsigned short* xwx    = (unsigned short*)(ws + 31457280);     // 64 MB
    float* cstate          = (float*)(ws + 98566144);              // 256 KB
    unsigned short* hbuf   = (unsigned short*)(ws + 98828288);     // 256 KB (2x ping-pong)
    float* wbuf            = (float*)(ws + 99090432);              // 4 KB
    int* wflag             = (int*)(ws + 99094528);                // 1 KB
    int* hflag             = (int*)(ws + 99095552);                // 1 KB

    (void)hipMemsetAsync(ws + 99094528, 0, 4096, stream);          // wflag + hflag

    k_cast_bf16<<<16384, 256, 0, stream>>>(x, xbf, 4194304);
    k_transpose_bf16<<<dim3(128, 16), 256, 0, stream>>>(Wx, WxT, 512);
    k_transpose_bf16<<<dim3(128, 32), 256, 0, stream>>>(Wh, WhT, 1024);
    k_transpose_bf16<<<dim3(128, 32), 256, 0, stream>>>(Wattn, WattnT, 1024);
    k_afl<<<4096, 256, 0, stream>>>(A, Afl);
    k_init<<<256, 256, 0, stream>>>(A, cstate, hbuf);

    k_gemm<<<dim3(32, 64), 256, 0, stream>>>(xbf, WxT, b, xwx, 8192, 4096, 512, 0);
    k_gemm<<<dim3(32, 8), 256, 0, stream>>>(Afl, WattnT, nullptr, P2, 1024, 4096, 1024, 1);

    k_recur<<<272, 256, 0, stream>>>(A, WhT, xwx, P2, cstate, hbuf, wbuf,
                                     wflag, hflag, out);
}

// Round 6
// 2033.484 us; speedup vs baseline: 1.5965x; 1.5965x over previous
//
#include <hip/hip_runtime.h>
#include <stdint.h>

// N=64, T=128, D=512, H=1024, 4H=4096.
// R5: persistent kernel; sync fabric rebuilt:
//   - NO agent release/acquire anywhere (no buffer_wbl2 / buffer_inv):
//     sc1 relaxed data stores -> __syncthreads (vmcnt drain) -> relaxed flag.
//   - Flags padded to one 128B line each; 2 aggregator wgs collapse the
//     128-producer fan-in; consumers poll ONE line with ONE thread.
//   - xwx/P2 epilogue operands prefetched into regs before the poll.
// Layout: 256 gemm wgs (R=wid>>7 rows, C=wid&127 cols), 16 score wgs
// (wids 256..271, 4 rows each), 2 aggregators (272,273). Grid 274, 2 wg/CU.

#define Tt 128
#define FH 4096

typedef __bf16 bf8 __attribute__((ext_vector_type(8)));
typedef float f4 __attribute__((ext_vector_type(4)));
typedef short s8v __attribute__((ext_vector_type(8)));
typedef unsigned long long ull;

__device__ __forceinline__ float bf2f(unsigned short u) {
    union { unsigned u32; float f; } x; x.u32 = ((unsigned)u) << 16; return x.f;
}
__device__ __forceinline__ unsigned short f2bf(float f) {
    union { float f32; unsigned u; } x; x.f32 = f;
    unsigned r = x.u + 0x7fffu + ((x.u >> 16) & 1u);
    return (unsigned short)(r >> 16);
}
__device__ __forceinline__ ull ald(const ull* p) {
    return __hip_atomic_load((ull*)p, __ATOMIC_RELAXED, __HIP_MEMORY_SCOPE_AGENT);
}
__device__ __forceinline__ void ast(ull* p, ull v) {
    __hip_atomic_store(p, v, __ATOMIC_RELAXED, __HIP_MEMORY_SCOPE_AGENT);
}
__device__ __forceinline__ int aldi(const int* p) {
    return __hip_atomic_load((int*)p, __ATOMIC_RELAXED, __HIP_MEMORY_SCOPE_AGENT);
}
__device__ __forceinline__ void asti(int* p, int v) {
    __hip_atomic_store(p, v, __ATOMIC_RELAXED, __HIP_MEMORY_SCOPE_AGENT);
}

// ---------------- converts / init ----------------

__global__ __launch_bounds__(256) void k_cast_bf16(const float* __restrict__ in,
                                                   unsigned short* __restrict__ out, int n) {
    int i = blockIdx.x * 256 + threadIdx.x;
    if (i < n) out[i] = f2bf(in[i]);
}

__global__ __launch_bounds__(256) void k_transpose_bf16(const float* __restrict__ W,
                                                        unsigned short* __restrict__ WT, int K) {
    __shared__ float tl[32][33];
    int c0 = blockIdx.x * 32, k0 = blockIdx.y * 32;
    int tx = threadIdx.x & 31, ty = threadIdx.x >> 5;
    #pragma unroll
    for (int i = 0; i < 32; i += 8) tl[ty + i][tx] = W[(size_t)(k0 + ty + i) * 4096 + c0 + tx];
    __syncthreads();
    #pragma unroll
    for (int i = 0; i < 32; i += 8) WT[(size_t)(c0 + ty + i) * K + k0 + tx] = f2bf(tl[tx][ty + i]);
}

__global__ __launch_bounds__(256) void k_afl(const float* __restrict__ A,
                                             unsigned short* __restrict__ Afl) {
    int idx = blockIdx.x * 256 + threadIdx.x;
    int k = idx & 1023, l = (idx >> 10) & 15, n = idx >> 14;
    Afl[idx] = f2bf(A[((size_t)n * 1024 + k) * 16 + l]);
}

__global__ __launch_bounds__(256) void k_init(const float* __restrict__ A,
                                              float* __restrict__ cstate,
                                              unsigned short* __restrict__ hbf) {
    int idx = blockIdx.x * 256 + threadIdx.x;   // 64*1024
    const float* ap = A + (size_t)idx * 16;
    float s = 0.f;
    #pragma unroll
    for (int l = 0; l < 16; l++) s += ap[l];
    float h = s * (1.0f / 16.0f);
    cstate[idx] = h;
    hbf[idx] = f2bf(h);
}

// ---------------- generic bf16 MFMA GEMM (preamble) ----------------
__global__ __launch_bounds__(256) void k_gemm(const unsigned short* __restrict__ A,
                                              const unsigned short* __restrict__ BT,
                                              const float* __restrict__ bias,
                                              unsigned short* __restrict__ out,
                                              int M, int Nn, int K, int mode) {
    __shared__ unsigned short As[128][40];
    __shared__ unsigned short Bs[128][40];
    int m0 = blockIdx.y * 128, n0 = blockIdx.x * 128;
    int tid = threadIdx.x, lane = tid & 63, wave = tid >> 6;
    int wr = wave >> 1, wc = wave & 1, quad = lane >> 4, l16 = lane & 15;
    f4 acc[4][4];
    #pragma unroll
    for (int i = 0; i < 4; i++)
        #pragma unroll
        for (int j = 0; j < 4; j++) acc[i][j] = f4{0.f, 0.f, 0.f, 0.f};

    for (int k0 = 0; k0 < K; k0 += 32) {
        __syncthreads();
        #pragma unroll
        for (int i = 0; i < 2; i++) {
            int idx = i * 256 + tid, r = idx >> 2, c = idx & 3;
            *(s8v*)&As[r][c * 8] = *(const s8v*)&A[(size_t)(m0 + r) * K + k0 + c * 8];
            *(s8v*)&Bs[r][c * 8] = *(const s8v*)&BT[(size_t)(n0 + r) * K + k0 + c * 8];
        }
        __syncthreads();
        bf8 af[4], bfr[4];
        #pragma unroll
        for (int i = 0; i < 4; i++) af[i] = *(const bf8*)&As[wr * 64 + i * 16 + l16][quad * 8];
        #pragma unroll
        for (int j = 0; j < 4; j++) bfr[j] = *(const bf8*)&Bs[wc * 64 + j * 16 + l16][quad * 8];
        #pragma unroll
        for (int i = 0; i < 4; i++)
            #pragma unroll
            for (int j = 0; j < 4; j++)
                acc[i][j] = __builtin_amdgcn_mfma_f32_16x16x32_bf16(af[i], bfr[j], acc[i][j], 0, 0, 0);
    }

    #pragma unroll
    for (int i = 0; i < 4; i++)
        #pragma unroll
        for (int j = 0; j < 4; j++) {
            int row0 = m0 + wr * 64 + i * 16 + quad * 4;
            int col = n0 + wc * 64 + j * 16 + l16;
            float bia = bias ? bias[col] : 0.0f;
            #pragma unroll
            for (int r = 0; r < 4; r++) {
                float v = acc[i][j][r] + bia;
                int rw = row0 + r;
                if (mode == 0) {
                    out[(size_t)rw * Nn + col] = f2bf(v);
                } else {
                    int n = rw >> 4, l = rw & 15;
                    out[((size_t)n * Nn + col) * 16 + l] = f2bf(v);
                }
            }
        }
}

// ---------------- persistent recurrent kernel ----------------
// Flags: hflagp[i*32] (i=wid, 0..255), wflagp[s*32] (s=0..15), aggh[g*32] (g=0,1).
__global__ __launch_bounds__(256, 2) void k_recur(
    const float* __restrict__ Afull,
    const unsigned short* __restrict__ WhT, const unsigned short* __restrict__ xwx,
    const unsigned short* __restrict__ P2, const float* __restrict__ cstate,
    unsigned short* __restrict__ hbuf,   // 2 x 65536 bf16 ping-pong
    float* __restrict__ wbuf,            // 64 x 16 f32 softmax weights
    int* __restrict__ wflagp, int* __restrict__ hflagp, int* __restrict__ aggh,
    float* __restrict__ out) {
    __shared__ unsigned short hL[32][1032];  // 66 KB (+8 pad/row)
    __shared__ float aL[32][33];
    __shared__ float wL[512];
    __shared__ unsigned short hpk[32][8];

    const int wid = blockIdx.x;
    const int tid = threadIdx.x, lane = tid & 63, wave = tid >> 6;
    ull* wbuf_u = (ull*)wbuf;

    if (wid >= 272) {
        // ---------------- aggregator wg: fan-in 128 producer flags ----------------
        const int g = wid - 272;
        for (int t = 1; t < Tt; ++t) {
            if (tid < 128) {
                while (aldi(&hflagp[(g * 128 + tid) * 32]) < t)
                    __builtin_amdgcn_s_sleep(2);
            }
            __syncthreads();
            if (tid == 0) asti(&aggh[g * 32], t);
        }
        return;
    }

    if (wid >= 256) {
        // ---------------- score wg: 4 rows, one per wave ----------------
        const int s = wid - 256;        // 0..15
        const int g = s >> 3;           // row group
        const int row = s * 4 + wave;   // n in 0..63
        const float* Ab = Afull + ((size_t)row * 1024 + lane * 16) * 16;

        for (int t = 0; t < Tt; ++t) {
            if (tid == 0) {
                while (aldi(&aggh[g * 32]) < t) __builtin_amdgcn_s_sleep(2);
            }
            __syncthreads();
            __builtin_amdgcn_fence(__ATOMIC_ACQUIRE, "workgroup");

            const ull* hb_u = (const ull*)(hbuf + (t & 1) * 65536);
            float hk[16];
            #pragma unroll
            for (int i = 0; i < 4; i++) {
                union { ull u; unsigned short h[4]; } cv;
                cv.u = ald(hb_u + (size_t)row * 256 + lane * 4 + i);
                #pragma unroll
                for (int j = 0; j < 4; j++) hk[i * 4 + j] = bf2f(cv.h[j]);
            }
            float part[16];
            #pragma unroll
            for (int l = 0; l < 16; l++) part[l] = 0.f;
            #pragma unroll
            for (int kk = 0; kk < 16; ++kk) {
                const f4* ar = (const f4*)(Ab + (size_t)kk * 16);
                f4 a0 = ar[0], a1 = ar[1], a2 = ar[2], a3 = ar[3];
                float hv = hk[kk];
                part[0]  += hv * a0.x;  part[1]  += hv * a0.y;
                part[2]  += hv * a0.z;  part[3]  += hv * a0.w;
                part[4]  += hv * a1.x;  part[5]  += hv * a1.y;
                part[6]  += hv * a1.z;  part[7]  += hv * a1.w;
                part[8]  += hv * a2.x;  part[9]  += hv * a2.y;
                part[10] += hv * a2.z;  part[11] += hv * a2.w;
                part[12] += hv * a3.x;  part[13] += hv * a3.y;
                part[14] += hv * a3.z;  part[15] += hv * a3.w;
            }
            #pragma unroll
            for (int l = 0; l < 16; l++) {
                float v = part[l];
                v += __shfl_down(v, 32, 64); v += __shfl_down(v, 16, 64);
                v += __shfl_down(v, 8, 64);  v += __shfl_down(v, 4, 64);
                v += __shfl_down(v, 2, 64);  v += __shfl_down(v, 1, 64);
                part[l] = v;
            }
            if (lane == 0) {
                float sc[16]; float mx = -1e30f;
                #pragma unroll
                for (int l = 0; l < 16; l++) {
                    sc[l] = part[l] * (1.0f / 32.0f);
                    mx = fmaxf(mx, sc[l]);
                }
                float sum = 0.f;
                #pragma unroll
                for (int l = 0; l < 16; l++) { sc[l] = __expf(sc[l] - mx); sum += sc[l]; }
                float inv = 1.0f / sum;
                #pragma unroll
                for (int i = 0; i < 8; i++) {
                    union { ull u; float f[2]; } cv;
                    cv.f[0] = sc[2 * i] * inv; cv.f[1] = sc[2 * i + 1] * inv;
                    ast(wbuf_u + row * 8 + i, cv.u);
                }
            }
            __syncthreads();   // drains all waves' wbuf stores (vmcnt 0 at barrier)
            if (tid == 0) asti(&wflagp[s * 32], t + 1);
        }
        return;
    }

    // ---------------- gemm wg ----------------
    const int R = wid >> 7, C = wid & 127;
    const int quad = lane >> 4, l16 = lane & 15;
    const int rr = wave >> 1, cc = wave & 1;
    const int n_l = tid & 31, jl = tid >> 5;
    const int myn = R * 32 + n_l, myj = C * 8 + jl;
    const int cl = cc * 16 + l16;
    const int acol = ((cl >> 3) << 10) + C * 8 + (cl & 7);
    const size_t bbase = (size_t)acol * 1024 + quad * 8;

    float creg = cstate[(size_t)myn * 1024 + myj];   // c0 = h0, register-resident

    for (int t = 0; t < Tt; ++t) {
        const ull* hb_u = (const ull*)(hbuf + (t & 1) * 65536);
        ull* hbW_u = (ull*)(hbuf + ((t + 1) & 1) * 65536);

        // ---- prefetch epilogue operands (overlap with flag wait) ----
        unsigned short xw[4];
        s8v p0v[4], p1v[4];
        #pragma unroll
        for (int r = 0; r < 4; r++) {
            int nl = rr * 16 + quad * 4 + r;
            int n = R * 32 + nl;
            xw[r] = xwx[((size_t)n * Tt + t) * FH + acol];
            const unsigned short* pp = P2 + ((size_t)n * FH + acol) * 16;
            p0v[r] = *(const s8v*)pp;
            p1v[r] = *(const s8v*)(pp + 8);
        }

        // ---- wait for h(t): one thread polls the aggregated group flag ----
        if (tid == 0) {
            while (aldi(&aggh[R * 32]) < t) __builtin_amdgcn_s_sleep(2);
        }
        __syncthreads();
        __builtin_amdgcn_fence(__ATOMIC_ACQUIRE, "workgroup");

        // ---- stage h(t) rows [32R,32R+32) into LDS ----
        #pragma unroll
        for (int it = 0; it < 32; ++it) {
            int idx = it * 256 + tid;
            int r2 = idx >> 8, c8 = idx & 255;
            ull v = ald(hb_u + ((size_t)(R * 32 + r2) << 8) + c8);
            *(ull*)&hL[r2][c8 * 4] = v;
        }
        __syncthreads();

        // ---- GEMM: h@Wh ----
        f4 acc = {0.f, 0.f, 0.f, 0.f};
        const unsigned short* hrow = &hL[rr * 16 + l16][quad * 8];
        #pragma unroll 8
        for (int ks = 0; ks < 32; ++ks) {
            bf8 a = *(const bf8*)(hrow + ks * 32);
            bf8 b = *(const bf8*)(WhT + bbase + ks * 32);
            acc = __builtin_amdgcn_mfma_f32_16x16x32_bf16(a, b, acc, 0, 0, 0);
        }

        // ---- softmax weights: poll 8 score-wg flags ----
        if (tid < 8) {
            while (aldi(&wflagp[(R * 8 + tid) * 32]) < t + 1)
                __builtin_amdgcn_s_sleep(2);
        }
        __syncthreads();
        __builtin_amdgcn_fence(__ATOMIC_ACQUIRE, "workgroup");
        {
            union { ull u; float f[2]; } cv;
            cv.u = ald(wbuf_u + R * 256 + tid);
            wL[tid * 2] = cv.f[0]; wL[tid * 2 + 1] = cv.f[1];
        }
        __syncthreads();

        // ---- epilogue: + xwx + attention (prefetched operands) -> aL ----
        #pragma unroll
        for (int r = 0; r < 4; r++) {
            int nl = rr * 16 + quad * 4 + r;
            float v = acc[r] + bf2f(xw[r]);
            float s = 0.f;
            #pragma unroll
            for (int l = 0; l < 8; l++) s += wL[nl * 16 + l] * bf2f((unsigned short)p0v[r][l]);
            #pragma unroll
            for (int l = 0; l < 8; l++) s += wL[nl * 16 + 8 + l] * bf2f((unsigned short)p1v[r][l]);
            aL[nl][cl] = v + s;
        }
        __syncthreads();

        // ---- gates (c register-resident) ----
        {
            float iv = aL[n_l][jl],      fv = aL[n_l][8 + jl];
            float ov = aL[n_l][16 + jl], gv = aL[n_l][24 + jl];
            float ig = 1.f / (1.f + __expf(-iv));
            float fg = 1.f / (1.f + __expf(-fv));
            float og = 1.f / (1.f + __expf(-ov));
            float gg = tanhf(gv);
            creg = fg * creg + ig * gg;
            float hv = og * tanhf(creg);
            __hip_atomic_store(&out[((size_t)myn * Tt + t) * 1024 + myj], hv,
                               __ATOMIC_RELAXED, __HIP_MEMORY_SCOPE_AGENT);
            hpk[n_l][jl] = f2bf(hv);
        }
        __syncthreads();

        // ---- publish h(t+1) chunk; barrier drains vmcnt; relaxed flag ----
        if (t < Tt - 1) {
            if (tid < 64) {
                int row = tid >> 1, half = tid & 1;
                ull v = *(const ull*)&hpk[row][half * 4];
                ast(hbW_u + ((size_t)(R * 32 + row) << 8) + C * 2 + half, v);
            }
            __syncthreads();
            if (tid == 0) asti(&hflagp[wid * 32], t + 1);
        }
    }
}

// ---------------- launch ----------------

extern "C" void kernel_launch(void* const* d_in, const int* in_sizes, int n_in,
                              void* d_out, int out_size, void* d_ws, size_t ws_size,
                              hipStream_t stream) {
    const float* x     = (const float*)d_in[0];   // [64][128][512]
    const float* A     = (const float*)d_in[1];   // [64][1024][16]
    const float* Wx    = (const float*)d_in[2];   // [512][4096]
    const float* Wh    = (const float*)d_in[3];   // [1024][4096]
    const float* Wattn = (const float*)d_in[4];   // [1024][4096]
    const float* b     = (const float*)d_in[5];   // [4096]
    float* out = (float*)d_out;
    char* ws = (char*)d_ws;

    unsigned short* xbf    = (unsigned short*)(ws);                // 8 MB; reused for P2
    unsigned short* P2     = (unsigned short*)(ws);                // alias (xbf dead by then)
    unsigned short* WxT    = (unsigned short*)(ws + 8388608);      // 4 MB
    unsigned short* WhT    = (unsigned short*)(ws + 12582912);     // 8 MB
    unsigned short* WattnT = (unsigned short*)(ws + 20971520);     // 8 MB
    unsigned short* Afl    = (unsigned short*)(ws + 29360128);     // 2 MB
    unsigned short* xwx    = (unsigned short*)(ws + 31457280);     // 64 MB
    float* cstate          = (float*)(ws + 98566144);              // 256 KB
    unsigned short* hbuf   = (unsigned short*)(ws + 98828288);     // 256 KB (2x ping-pong)
    float* wbuf            = (float*)(ws + 99090432);              // 4 KB
    int* hflagp            = (int*)(ws + 99094528);                // 32 KB (256 padded)
    int* wflagp            = (int*)(ws + 99127296);                // 2 KB (16 padded)
    int* aggh              = (int*)(ws + 99129344);                // 256 B (2 padded)

    (void)hipMemsetAsync(ws + 99094528, 0, 36864, stream);         // all flags

    k_cast_bf16<<<16384, 256, 0, stream>>>(x, xbf, 4194304);
    k_transpose_bf16<<<dim3(128, 16), 256, 0, stream>>>(Wx, WxT, 512);
    k_transpose_bf16<<<dim3(128, 32), 256, 0, stream>>>(Wh, WhT, 1024);
    k_transpose_bf16<<<dim3(128, 32), 256, 0, stream>>>(Wattn, WattnT, 1024);
    k_afl<<<4096, 256, 0, stream>>>(A, Afl);
    k_init<<<256, 256, 0, stream>>>(A, cstate, hbuf);

    k_gemm<<<dim3(32, 64), 256, 0, stream>>>(xbf, WxT, b, xwx, 8192, 4096, 512, 0);
    k_gemm<<<dim3(32, 8), 256, 0, stream>>>(Afl, WattnT, nullptr, P2, 1024, 4096, 1024, 1);

    k_recur<<<274, 256, 0, stream>>>(A, WhT, xwx, P2, cstate, hbuf, wbuf,
                                     wflagp, hflagp, aggh, out);
}